// Round 3
// baseline (137.920 us; speedup 1.0000x reference)
//
#include <hip/hip_runtime.h>

#define HH 192
#define WW 192
#define VV 1024
#define FF 2048
#define NPIX (HH*WW)
#define SIG 0.01f
#define EPSF 1e-7f
#define LOG2E 1.4426950408889634f
#define BAND_T 15.0f                 // |arg| threshold (log2 units) for exact eval
#define C_OUT 1.4426943e-7f          // log2(1+EPSF)
#define C_IN  (-23.2534966642f)      // log2(EPSF)
#define NTILE 576                    // 24x24 tiles of 8x8 px; tile == one wave
#define NQ 4                         // face quarters per tile (load balance)
#define FQ (FF/NQ)                   // 512 faces per quarter

// ws layout (floats):
// [0, NPIX)            logmiss, tile-swizzled: p = tile*64 + lane
// [NPIX, NPIX+NTILE)   done counters (int)
// [A, A+9*FF)          coeffs SoA: coeffs[e*FF + f], e in 0..8
//                      arg_i = A_i*py + B_i*px + C_i; order A0 B0 C0 A1 B1 C1 A2 B2 C2
// [A+9*FF]             loss scale factor

__global__ void __launch_bounds__(256)
prep_kernel(const float* __restrict__ verts, const int* __restrict__ faces,
            const float* __restrict__ cam, float* __restrict__ coeffs,
            float* __restrict__ logmiss, int* __restrict__ done,
            float* __restrict__ factor_out, float* __restrict__ out) {
    const int b = blockIdx.x, tid = threadIdx.x;
    if (b < NPIX / 256) {               // 144 blocks: zero logmiss
        logmiss[b * 256 + tid] = 0.0f;
        return;
    }
    if (b == 144) {                     // zero done counters
        for (int i = tid; i < NTILE; i += 256) done[i] = 0;
        return;
    }
    // b in 145..152: coefficient blocks, 256 faces each (vertices projected redundantly)
    __shared__ float sx[VV], sy[VV];
    const float cx = cam[0], cy = cam[1], cz = cam[2];
    const float nrm = sqrtf(cx*cx + cy*cy + cz*cz);
    const float inv = 1.0f / fmaxf(nrm, 1e-8f);
    const float zx = -cx*inv, zy = -cy*inv, zz = -cz*inv;
    float xx = zz, xz = -zx;
    const float invx = 1.0f / fmaxf(sqrtf(xx*xx + xz*xz), 1e-8f);
    xx *= invx; xz *= invx;
    const float yx = zy*xz;
    const float yy = zz*xx - zx*xz;
    const float yz = -zy*xx;
    const float ratio = 0.57735026918962576f;   // tan(30 deg)

    for (int i = tid; i < VV; i += 256) {
        const float vx = verts[3*i+0] - cx;
        const float vy = verts[3*i+1] - cy;
        const float vz = verts[3*i+2] - cz;
        const float pcx = xx*vx + xz*vz;
        const float pcy = yx*vx + yy*vy + yz*vz;
        float pcz = zx*vx + zy*vy + zz*vz;
        pcz = fmaxf(pcz, 1e-5f);
        const float iz = 1.0f / (pcz * ratio);
        sx[i] = pcx * iz;
        sy[i] = pcy * iz;
    }
    __syncthreads();

    const int f = (b - 145) * 256 + tid;
    const int i0 = faces[3*f+0], i1 = faces[3*f+1], i2 = faces[3*f+2];
    const float p0x = sx[i0], p0y = sy[i0];
    const float p1x = sx[i1], p1y = sy[i1];
    const float p2x = sx[i2], p2y = sy[i2];
    const float e0x = p1x-p0x, e0y = p1y-p0y;
    const float e1x = p2x-p1x, e1y = p2y-p1y;
    const float e2x = p0x-p2x, e2y = p0y-p2y;
    const float c0 = e0y*p0x - e0x*p0y;
    const float c1 = e1y*p1x - e1x*p1y;
    const float c2 = e2y*p2x - e2x*p2y;
    const float area2 = e0x*(p2y-p0y) - e0y*(p2x-p0x);
    const float sgn = (area2 >= 0.0f) ? 1.0f : -1.0f;
    const float l0 = fmaxf(sqrtf(e0x*e0x + e0y*e0y), 1e-8f);
    const float l1 = fmaxf(sqrtf(e1x*e1x + e1y*e1y), 1e-8f);
    const float l2 = fmaxf(sqrtf(e2x*e2x + e2y*e2y), 1e-8f);
    // t_i = exp2(a_i); sigmoid(d_i/SIG) = 1/(1+t_i); a_i = m*(e.x*py - e.y*px + c)
    const float m0 = -sgn * (LOG2E/SIG) / l0;
    const float m1 = -sgn * (LOG2E/SIG) / l1;
    const float m2 = -sgn * (LOG2E/SIG) / l2;
    coeffs[0*FF+f] = m0*e0x;  coeffs[1*FF+f] = -m0*e0y;  coeffs[2*FF+f] = m0*c0;
    coeffs[3*FF+f] = m1*e1x;  coeffs[4*FF+f] = -m1*e1y;  coeffs[5*FF+f] = m1*c1;
    coeffs[6*FF+f] = m2*e2x;  coeffs[7*FF+f] = -m2*e2y;  coeffs[8*FF+f] = m2*c2;

    if (b == 145 && tid == 0) {
        const float dist = sqrtf(cx*cx + cy*cy + cz*cz);
        *factor_out = 1.0f + fmaxf(6.0f - dist, 0.0f);
        *out = 0.0f;
    }
}

__global__ void __launch_bounds__(64)
main_kernel(const float* __restrict__ coeffs, const float* __restrict__ ref,
            const float* __restrict__ factor, float* __restrict__ logmiss,
            int* __restrict__ done, float* __restrict__ out) {
    const int bid = blockIdx.x;
    const int t = bid >> 2, q = bid & 3;
    const int l = threadIdx.x;
    const int tx = t % 24, ty = t / 24;
    const int x = tx*8 + (l & 7), y = ty*8 + (l >> 3);
    const float px = (x + 0.5f) * (2.0f/WW) - 1.0f;
    const float py = 1.0f - (y + 0.5f) * (2.0f/HH);
    // tile interval: px in xc+-hx, py in yc+-hy
    const float xc = (tx*8 + 4.0f) * (2.0f/WW) - 1.0f;
    const float yc = 1.0f - (ty*8 + 4.0f) * (2.0f/HH);
    const float hx = 3.5f * (2.0f/WW), hy = 3.5f * (2.0f/HH);
    const float dIn = C_IN - C_OUT;

    float acc = FQ * C_OUT;             // baseline: every face contributes log2(1+eps)
    const int fbase = q * FQ;

    for (int r = 0; r < FQ/64; ++r) {   // 8 rounds of 64 faces (one per lane)
        const int f = fbase + r*64 + l;
        const float A0 = coeffs[0*FF+f], B0 = coeffs[1*FF+f], C0 = coeffs[2*FF+f];
        const float A1 = coeffs[3*FF+f], B1 = coeffs[4*FF+f], C1 = coeffs[5*FF+f];
        const float A2 = coeffs[6*FF+f], B2 = coeffs[7*FF+f], C2 = coeffs[8*FF+f];
        const float ac0 = fmaf(A0, yc, fmaf(B0, xc, C0));
        const float ac1 = fmaf(A1, yc, fmaf(B1, xc, C1));
        const float ac2 = fmaf(A2, yc, fmaf(B2, xc, C2));
        const float sp0 = fmaf(fabsf(A0), hy, fabsf(B0)*hx);
        const float sp1 = fmaf(fabsf(A1), hy, fabsf(B1)*hx);
        const float sp2 = fmaf(fabsf(A2), hy, fabsf(B2)*hx);
        // skip: tile entirely beyond one edge (contribution == C_OUT exactly-ish)
        const bool skip = (ac0 - sp0 >= BAND_T) || (ac1 - sp1 >= BAND_T) || (ac2 - sp2 >= BAND_T);
        // deep: tile entirely deep inside all edges (contribution == C_IN)
        const bool deep = (ac0 + sp0 <= -BAND_T) && (ac1 + sp1 <= -BAND_T) && (ac2 + sp2 <= -BAND_T);
        acc += (float)__popcll(__ballot(deep)) * dIn;   // wave-uniform add, all 64 px
        unsigned long long mb = __ballot(!skip && !deep);
        while (mb) {                    // wave-uniform loop over band faces
            const int src = __builtin_ctzll(mb); mb &= mb - 1;
#define RL(v) __int_as_float(__builtin_amdgcn_readlane(__float_as_int(v), src))
            const float a0 = fmaf(RL(A0), py, fmaf(RL(B0), px, RL(C0)));
            const float a1 = fmaf(RL(A1), py, fmaf(RL(B1), px, RL(C1)));
            const float a2 = fmaf(RL(A2), py, fmaf(RL(B2), px, RL(C2)));
#undef RL
            const float t0 = __builtin_amdgcn_exp2f(a0);
            const float t1 = __builtin_amdgcn_exp2f(a1);
            const float t2 = __builtin_amdgcn_exp2f(a2);
            const float P = (1.0f + t0) * (1.0f + t1) * (1.0f + t2);
            const float v = (1.0f + EPSF) - __builtin_amdgcn_rcpf(P);
            acc += __builtin_amdgcn_logf(v) - C_OUT;    // log2
        }
    }

    const int p = t*64 + l;             // tile-swizzled pixel slot
    atomicAdd(&logmiss[p], acc);
    __threadfence();                    // make logmiss adds visible before counter bump
    int old0 = 0;
    if (l == 0) old0 = atomicAdd(&done[t], 1);
    const int old = __shfl(old0, 0, 64);
    if (old == NQ - 1) {                // last quarter finishes the tile
        __threadfence();
        const float S = atomicAdd(&logmiss[p], 0.0f);   // coherent read at L2
        const float img = 1.0f - __builtin_amdgcn_exp2f(S);
        const float d = ref[y*WW + x] - img;
        float sq = d * d;
        #pragma unroll
        for (int off = 32; off > 0; off >>= 1)
            sq += __shfl_down(sq, off, 64);
        if (l == 0) atomicAdd(out, sq * factor[0]);
    }
}

extern "C" void kernel_launch(void* const* d_in, const int* in_sizes, int n_in,
                              void* d_out, int out_size, void* d_ws, size_t ws_size,
                              hipStream_t stream) {
    const float* verts = (const float*)d_in[0];   // (1,1024,3) f32
    const int*   faces = (const int*)d_in[1];     // (1,2048,3) i32
    const float* ref   = (const float*)d_in[2];   // (192,192) f32
    const float* cam   = (const float*)d_in[3];   // (3,) f32
    float* out = (float*)d_out;

    float* ws      = (float*)d_ws;
    float* logmiss = ws;                           // NPIX
    int*   done    = (int*)(ws + NPIX);            // NTILE
    float* coeffs  = ws + NPIX + NTILE;            // 9*FF
    float* factor  = ws + NPIX + NTILE + 9*FF;     // 1

    prep_kernel<<<153, 256, 0, stream>>>(verts, faces, cam, coeffs,
                                         logmiss, done, factor, out);
    main_kernel<<<NTILE*NQ, 64, 0, stream>>>(coeffs, ref, factor, logmiss, done, out);
}

// Round 4
// 86.070 us; speedup vs baseline: 1.6024x; 1.6024x over previous
//
#include <hip/hip_runtime.h>

#define HH 192
#define WW 192
#define VV 1024
#define FF 2048
#define NPIX (HH*WW)
#define SIG 0.01f
#define EPSF 1e-7f
#define LOG2E 1.4426950408889634f
#define BAND_T 15.0f                 // |arg| threshold (log2 units) for exact eval
#define C_OUT 1.4426943e-7f          // log2(1+EPSF)
#define C_IN  (-23.2534966642f)      // log2(EPSF)
#define NTILE 576                    // 24x24 tiles of 8x8 px; tile == one wave

// ws layout (floats):
// [0, NPIX)            logmiss, tile-swizzled: p = tile*64 + lane
// [NPIX, NPIX+9*FF)    coeffs SoA: coeffs[e*FF + f], e in 0..8
//                      arg_i = A_i*py + B_i*px + C_i; order A0 B0 C0 A1 B1 C1 A2 B2 C2
// [NPIX+9*FF]          loss scale factor

__global__ void __launch_bounds__(256)
prep_kernel(const float* __restrict__ verts, const int* __restrict__ faces,
            const float* __restrict__ cam, float* __restrict__ coeffs,
            float* __restrict__ logmiss, float* __restrict__ factor_out,
            float* __restrict__ out) {
    const int b = blockIdx.x, tid = threadIdx.x;
    if (b < NPIX / 256) {               // 144 blocks: zero logmiss
        logmiss[b * 256 + tid] = 0.0f;
        return;
    }
    // b in 144..151: coefficient blocks, 256 faces each (vertices projected redundantly)
    __shared__ float sx[VV], sy[VV];
    const float cx = cam[0], cy = cam[1], cz = cam[2];
    const float nrm = sqrtf(cx*cx + cy*cy + cz*cz);
    const float inv = 1.0f / fmaxf(nrm, 1e-8f);
    const float zx = -cx*inv, zy = -cy*inv, zz = -cz*inv;
    float xx = zz, xz = -zx;
    const float invx = 1.0f / fmaxf(sqrtf(xx*xx + xz*xz), 1e-8f);
    xx *= invx; xz *= invx;
    const float yx = zy*xz;
    const float yy = zz*xx - zx*xz;
    const float yz = -zy*xx;
    const float ratio = 0.57735026918962576f;   // tan(30 deg)

    for (int i = tid; i < VV; i += 256) {
        const float vx = verts[3*i+0] - cx;
        const float vy = verts[3*i+1] - cy;
        const float vz = verts[3*i+2] - cz;
        const float pcx = xx*vx + xz*vz;
        const float pcy = yx*vx + yy*vy + yz*vz;
        float pcz = zx*vx + zy*vy + zz*vz;
        pcz = fmaxf(pcz, 1e-5f);
        const float iz = 1.0f / (pcz * ratio);
        sx[i] = pcx * iz;
        sy[i] = pcy * iz;
    }
    __syncthreads();

    const int f = (b - 144) * 256 + tid;
    const int i0 = faces[3*f+0], i1 = faces[3*f+1], i2 = faces[3*f+2];
    const float p0x = sx[i0], p0y = sy[i0];
    const float p1x = sx[i1], p1y = sy[i1];
    const float p2x = sx[i2], p2y = sy[i2];
    const float e0x = p1x-p0x, e0y = p1y-p0y;
    const float e1x = p2x-p1x, e1y = p2y-p1y;
    const float e2x = p0x-p2x, e2y = p0y-p2y;
    const float c0 = e0y*p0x - e0x*p0y;
    const float c1 = e1y*p1x - e1x*p1y;
    const float c2 = e2y*p2x - e2x*p2y;
    const float area2 = e0x*(p2y-p0y) - e0y*(p2x-p0x);
    const float sgn = (area2 >= 0.0f) ? 1.0f : -1.0f;
    const float l0 = fmaxf(sqrtf(e0x*e0x + e0y*e0y), 1e-8f);
    const float l1 = fmaxf(sqrtf(e1x*e1x + e1y*e1y), 1e-8f);
    const float l2 = fmaxf(sqrtf(e2x*e2x + e2y*e2y), 1e-8f);
    // t_i = exp2(a_i); sigmoid(d_i/SIG) = 1/(1+t_i); a_i = m*(e.x*py - e.y*px + c)
    const float m0 = -sgn * (LOG2E/SIG) / l0;
    const float m1 = -sgn * (LOG2E/SIG) / l1;
    const float m2 = -sgn * (LOG2E/SIG) / l2;
    coeffs[0*FF+f] = m0*e0x;  coeffs[1*FF+f] = -m0*e0y;  coeffs[2*FF+f] = m0*c0;
    coeffs[3*FF+f] = m1*e1x;  coeffs[4*FF+f] = -m1*e1y;  coeffs[5*FF+f] = m1*c1;
    coeffs[6*FF+f] = m2*e2x;  coeffs[7*FF+f] = -m2*e2y;  coeffs[8*FF+f] = m2*c2;

    if (b == 144 && tid == 0) {
        const float dist = sqrtf(cx*cx + cy*cy + cz*cz);
        *factor_out = 1.0f + fmaxf(6.0f - dist, 0.0f);
        *out = 0.0f;
    }
}

// One wave = one (tile, 64-face chunk) work item. 576 tiles x 32 chunks
// = 18432 waves in 4608 blocks of 256 -> ~72 waves/CU queued, no tail.
__global__ void __launch_bounds__(256)
main_kernel(const float* __restrict__ coeffs, float* __restrict__ logmiss) {
    const int t = blockIdx.x;                        // tile 0..575
    const int w = threadIdx.x >> 6, l = threadIdx.x & 63;
    const int chunk = blockIdx.y * 4 + w;            // 0..31
    const int f = chunk * 64 + l;                    // this lane's face

    const int tx = t % 24, ty = t / 24;
    const int x = tx*8 + (l & 7), y = ty*8 + (l >> 3);
    const float px = (x + 0.5f) * (2.0f/WW) - 1.0f;
    const float py = 1.0f - (y + 0.5f) * (2.0f/HH);
    const float xc = (tx*8 + 4.0f) * (2.0f/WW) - 1.0f;
    const float yc = 1.0f - (ty*8 + 4.0f) * (2.0f/HH);
    const float hx = 3.5f * (2.0f/WW), hy = 3.5f * (2.0f/HH);
    const float dIn = C_IN - C_OUT;

    // lane-parallel load + interval classification of 64 faces
    const float A0 = coeffs[0*FF+f], B0 = coeffs[1*FF+f], C0 = coeffs[2*FF+f];
    const float A1 = coeffs[3*FF+f], B1 = coeffs[4*FF+f], C1 = coeffs[5*FF+f];
    const float A2 = coeffs[6*FF+f], B2 = coeffs[7*FF+f], C2 = coeffs[8*FF+f];
    const float ac0 = fmaf(A0, yc, fmaf(B0, xc, C0));
    const float ac1 = fmaf(A1, yc, fmaf(B1, xc, C1));
    const float ac2 = fmaf(A2, yc, fmaf(B2, xc, C2));
    const float sp0 = fmaf(fabsf(A0), hy, fabsf(B0)*hx);
    const float sp1 = fmaf(fabsf(A1), hy, fabsf(B1)*hx);
    const float sp2 = fmaf(fabsf(A2), hy, fabsf(B2)*hx);
    // skip: tile entirely beyond one edge (contribution == C_OUT)
    const bool skip = (ac0 - sp0 >= BAND_T) || (ac1 - sp1 >= BAND_T) || (ac2 - sp2 >= BAND_T);
    // deep: tile entirely deep inside all edges (contribution == C_IN)
    const bool deep = (ac0 + sp0 <= -BAND_T) && (ac1 + sp1 <= -BAND_T) && (ac2 + sp2 <= -BAND_T);

    float acc = 64.0f * C_OUT + (float)__popcll(__ballot(deep)) * dIn;
    unsigned long long mb = __ballot(!skip && !deep);
    while (mb) {                        // wave-uniform loop over band faces
        const int src = __builtin_ctzll(mb); mb &= mb - 1;
#define RL(v) __int_as_float(__builtin_amdgcn_readlane(__float_as_int(v), src))
        const float a0 = fmaf(RL(A0), py, fmaf(RL(B0), px, RL(C0)));
        const float a1 = fmaf(RL(A1), py, fmaf(RL(B1), px, RL(C1)));
        const float a2 = fmaf(RL(A2), py, fmaf(RL(B2), px, RL(C2)));
#undef RL
        const float t0 = __builtin_amdgcn_exp2f(a0);
        const float t1 = __builtin_amdgcn_exp2f(a1);
        const float t2 = __builtin_amdgcn_exp2f(a2);
        const float P = (1.0f + t0) * (1.0f + t1) * (1.0f + t2);
        const float v = (1.0f + EPSF) - __builtin_amdgcn_rcpf(P);
        acc += __builtin_amdgcn_logf(v) - C_OUT;    // log2 domain
    }
    atomicAdd(&logmiss[t*64 + l], acc);
}

__global__ void __launch_bounds__(256)
loss_kernel(const float* __restrict__ logmiss, const float* __restrict__ ref,
            const float* __restrict__ factor, float* __restrict__ out) {
    const int p = blockIdx.x * 256 + threadIdx.x;
    const int w = p >> 6, l = p & 63;
    const int x = (w % 24) * 8 + (l & 7);
    const int y = (w / 24) * 8 + (l >> 3);
    const float s = logmiss[p];
    const float image = 1.0f - __builtin_amdgcn_exp2f(s);
    const float d = ref[y*WW + x] - image;
    float sq = d * d;
    #pragma unroll
    for (int off = 32; off > 0; off >>= 1)
        sq += __shfl_down(sq, off, 64);
    __shared__ float wsum[4];
    const int lane = threadIdx.x & 63, wave = threadIdx.x >> 6;
    if (lane == 0) wsum[wave] = sq;
    __syncthreads();
    if (threadIdx.x == 0) {
        const float tot = (wsum[0] + wsum[1] + wsum[2] + wsum[3]) * factor[0];
        atomicAdd(out, tot);
    }
}

extern "C" void kernel_launch(void* const* d_in, const int* in_sizes, int n_in,
                              void* d_out, int out_size, void* d_ws, size_t ws_size,
                              hipStream_t stream) {
    const float* verts = (const float*)d_in[0];   // (1,1024,3) f32
    const int*   faces = (const int*)d_in[1];     // (1,2048,3) i32
    const float* ref   = (const float*)d_in[2];   // (192,192) f32
    const float* cam   = (const float*)d_in[3];   // (3,) f32
    float* out = (float*)d_out;

    float* ws      = (float*)d_ws;
    float* logmiss = ws;                           // NPIX
    float* coeffs  = ws + NPIX;                    // 9*FF
    float* factor  = ws + NPIX + 9*FF;             // 1

    prep_kernel<<<152, 256, 0, stream>>>(verts, faces, cam, coeffs,
                                         logmiss, factor, out);
    main_kernel<<<dim3(NTILE, 8), 256, 0, stream>>>(coeffs, logmiss);
    loss_kernel<<<NPIX/256, 256, 0, stream>>>(logmiss, ref, factor, out);
}